// Round 11
// baseline (99.493 us; speedup 1.0000x reference)
//
#include <hip/hip_runtime.h>
#include <math.h>

#define BATCH 4
#define NPTS  8192
#define TOTAL (BATCH * NPTS)            // 32768 points per set
#define TPB   256

#define WPB    4                        // waves per block
#define ROWS_PER_BLOCK (32 * WPB)       // 128 set1 rows per block
#define COLCH  8                        // set2 sweep chunks
#define SWEEP  (NPTS / COLCH)           // 1024 set2 cols per wave sweep
#define NT     (SWEEP / 32)             // 32 B-tiles per sweep

typedef __bf16 bf16v8 __attribute__((ext_vector_type(8)));
typedef float  f32x16 __attribute__((ext_vector_type(16)));

// ws layout:
//   Af: ushort[TOTAL*16] @ 0    (1 MB)  A-form K-vectors of set1 (rows)
//   Bf: ushort[TOTAL*16] @ 1 MB (1 MB)  B-form K-vectors of set2 (cols)
//   minbuf: uint[2*TOTAL] @ 2 MB (256 KB) dist1 then dist2 (ordered-uint)
//   (1-ahead B prefetch over-reads <=1KB past Bf into minbuf -- mapped, harmless)

__device__ __forceinline__ unsigned f2ord(float f) {
  unsigned b = __float_as_uint(f);
  return ((int)b >= 0) ? (b ^ 0x80000000u) : ~b;
}
__device__ __forceinline__ float ord2f(unsigned k) {
  unsigned b = (k & 0x80000000u) ? (k ^ 0x80000000u) : ~k;
  return __uint_as_float(b);
}
__device__ __forceinline__ unsigned short f2bf(float f) {   // RNE
  unsigned u = __float_as_uint(f);
  return (unsigned short)((u + 0x7fffu + ((u >> 16) & 1u)) >> 16);
}
__device__ __forceinline__ float bf2f(unsigned short h) {
  return __uint_as_float(((unsigned)h) << 16);
}

// K-slot pairing (A[k]*B[k]), verified absmax 0 since R4:
//  k0-2: ah*ch   k3-5: al*ch   k6-8: ah*cl   (c = -2b)
//  k9,10: sq_a{h,l} * 1,1      k11,12: 1,1 * sq_b{h,l}     k13-15: 0
// One thread packs A-form of x1[j] AND B-form of x2[j].
__global__ __launch_bounds__(TPB) void pack_kernel(
    const float* __restrict__ x1, const float* __restrict__ x2,
    unsigned short* __restrict__ Af, unsigned short* __restrict__ Bf,
    unsigned* __restrict__ minbuf, float* __restrict__ out) {
  int i = blockIdx.x * TPB + threadIdx.x;   // 0 .. TOTAL-1
  if (i == 0) out[0] = 0.0f;
  minbuf[i] = 0xFFFFFFFFu;
  minbuf[TOTAL + i] = 0xFFFFFFFFu;
  const unsigned short one = 0x3F80;

  // A-form from set1
  {
    float x = x1[3 * i + 0], y = x1[3 * i + 1], z = x1[3 * i + 2];
    float sq = fmaf(x, x, fmaf(y, y, z * z));
    unsigned short sh = f2bf(sq);
    unsigned short sl = f2bf(sq - bf2f(sh));
    unsigned short hx = f2bf(x), hy = f2bf(y), hz = f2bf(z);
    unsigned short lx = f2bf(x - bf2f(hx)), ly = f2bf(y - bf2f(hy)), lz = f2bf(z - bf2f(hz));
    unsigned short v[16] = {hx, hy, hz, lx, ly, lz, hx, hy, hz,
                            sh, sl, one, one, 0, 0, 0};
    uint4* dst = (uint4*)(Af + (size_t)i * 16);
    uint4 w0, w1;
    w0.x = v[0] | ((unsigned)v[1] << 16);  w0.y = v[2] | ((unsigned)v[3] << 16);
    w0.z = v[4] | ((unsigned)v[5] << 16);  w0.w = v[6] | ((unsigned)v[7] << 16);
    w1.x = v[8] | ((unsigned)v[9] << 16);  w1.y = v[10] | ((unsigned)v[11] << 16);
    w1.z = v[12] | ((unsigned)v[13] << 16); w1.w = v[14] | ((unsigned)v[15] << 16);
    dst[0] = w0; dst[1] = w1;
  }
  // B-form from set2
  {
    float x = x2[3 * i + 0], y = x2[3 * i + 1], z = x2[3 * i + 2];
    float sq = fmaf(x, x, fmaf(y, y, z * z));
    unsigned short sh = f2bf(sq);
    unsigned short sl = f2bf(sq - bf2f(sh));
    float cx = -2.0f * x, cy = -2.0f * y, cz = -2.0f * z;
    unsigned short chx = f2bf(cx), chy = f2bf(cy), chz = f2bf(cz);
    unsigned short clx = f2bf(cx - bf2f(chx)), cly = f2bf(cy - bf2f(chy)), clz = f2bf(cz - bf2f(chz));
    unsigned short v[16] = {chx, chy, chz, chx, chy, chz, clx, cly, clz,
                            one, one, sh, sl, 0, 0, 0};
    uint4* dst = (uint4*)(Bf + (size_t)i * 16);
    uint4 w0, w1;
    w0.x = v[0] | ((unsigned)v[1] << 16);  w0.y = v[2] | ((unsigned)v[3] << 16);
    w0.z = v[4] | ((unsigned)v[5] << 16);  w0.w = v[6] | ((unsigned)v[7] << 16);
    w1.x = v[8] | ((unsigned)v[9] << 16);  w1.y = v[10] | ((unsigned)v[11] << 16);
    w1.z = v[12] | ((unsigned)v[13] << 16); w1.w = v[14] | ((unsigned)v[15] << 16);
    dst[0] = w0; dst[1] = w1;
  }
}

// COMBINED single pass: each MFMA tile (32 set1 rows x 32 set2 cols) feeds
// BOTH outputs. rowacc: elementwise v_min (1 AGPR operand per op, legal
// direct-AGPR read). col fold: two 8-deep chains (1 AGPR operand per op).
// Butterfly for rows runs ONCE per sweep (amortized ~3 ops/tile).
__global__ __launch_bounds__(TPB, 6) void min_kernel(
    const unsigned short* __restrict__ Af, const unsigned short* __restrict__ Bf,
    unsigned* __restrict__ minbuf) {
  const int b   = blockIdx.z;
  const int tid = threadIdx.x;
  const int wave = tid >> 6, lane = tid & 63;
  const int g = lane >> 5, l31 = lane & 31;

  const int rowbase = blockIdx.x * ROWS_PER_BLOCK + wave * 32;  // set1 rows
  const int colbase = blockIdx.y * SWEEP;                        // set2 cols

  // fixed A fragment: this wave's 32 set1 rows
  const bf16v8 af = *((const bf16v8*)Af + (size_t)(b * NPTS + rowbase + l31) * 2 + g);

  f32x16 zc;
#pragma unroll
  for (int q = 0; q < 16; ++q) zc[q] = 0.0f;

  float rowacc[16];
#pragma unroll
  for (int q = 0; q < 16; ++q) rowacc[q] = INFINITY;

  unsigned* __restrict__ d2 = minbuf + TOTAL + b * NPTS + colbase;
  const bf16v8* bp = (const bf16v8*)Bf + (size_t)(b * NPTS + colbase + l31) * 2 + g;

  bf16v8 bcur = bp[0];
  for (int ti = 0; ti < NT; ++ti) {
    bf16v8 bnext = bp[64];                 // 1-ahead prefetch (last iter dead)
    f32x16 acc = __builtin_amdgcn_mfma_f32_32x32x16_bf16(af, bcur, zc, 0, 0, 0);

    // dist1 side: elementwise running min (16 ops, single-AGPR each)
#pragma unroll
    for (int q = 0; q < 16; ++q) rowacc[q] = fminf(rowacc[q], acc[q]);

    // dist2 side: fold 16 rows -> 1, two parallel chains (single-AGPR each)
    float ce = acc[0], co = acc[1];
#pragma unroll
    for (int k = 1; k < 8; ++k) {
      ce = fminf(ce, acc[2 * k]);
      co = fminf(co, acc[2 * k + 1]);
    }
    float m = fminf(ce, co);
    m = fminf(m, __shfl_xor(m, 32));       // merge g-halves (32 rows total)
    if (g == 0) atomicMin(&d2[ti * 32 + l31], f2ord(m));

    bcur = bnext;
    bp += 64;
  }

  // dist1 tail: butterfly min across the 32 col-lanes, once per sweep
#pragma unroll
  for (int q = 0; q < 16; ++q) {
    float v = rowacc[q];
    v = fminf(v, __shfl_xor(v, 16));
    v = fminf(v, __shfl_xor(v, 8));
    v = fminf(v, __shfl_xor(v, 4));
    v = fminf(v, __shfl_xor(v, 2));
    v = fminf(v, __shfl_xor(v, 1));
    if (l31 == 0) {
      int row = rowbase + (q & 3) + 8 * (q >> 2) + 4 * g;
      atomicMin(&minbuf[b * NPTS + row], f2ord(v));
    }
  }
}

__global__ __launch_bounds__(TPB) void finalize_kernel(
    const unsigned* __restrict__ minbuf, float* __restrict__ out, float scale) {
  int idx = blockIdx.x * TPB + threadIdx.x;   // 0 .. 2*TOTAL-1
  float v = ord2f(minbuf[idx]) * scale;
  for (int off = 32; off > 0; off >>= 1) v += __shfl_down(v, off);
  __shared__ float ls[TPB / 64];
  if ((threadIdx.x & 63) == 0) ls[threadIdx.x >> 6] = v;
  __syncthreads();
  if (threadIdx.x == 0) {
    float t = 0.0f;
#pragma unroll
    for (int w = 0; w < TPB / 64; ++w) t += ls[w];
    atomicAdd(out, t);
  }
}

extern "C" void kernel_launch(void* const* d_in, const int* in_sizes, int n_in,
                              void* d_out, int out_size, void* d_ws, size_t ws_size,
                              hipStream_t stream) {
  const float* xyz1 = (const float*)d_in[0];
  const float* xyz2 = (const float*)d_in[1];
  float* out = (float*)d_out;

  char* ws = (char*)d_ws;
  unsigned short* Af = (unsigned short*)(ws);
  unsigned short* Bf = (unsigned short*)(ws + (size_t)TOTAL * 32);
  unsigned*   minbuf = (unsigned*)(ws + (size_t)2 * TOTAL * 32);

  // 1) pack set1 A-form + set2 B-form + init minbuf + zero out
  pack_kernel<<<dim3(TOTAL / TPB), dim3(TPB), 0, stream>>>(
      xyz1, xyz2, Af, Bf, minbuf, out);

  // 2) ONE combined pass over the pair space: 64 x 8 x 4 = 2048 blocks
  dim3 mgrid(NPTS / ROWS_PER_BLOCK, COLCH, BATCH);
  min_kernel<<<mgrid, dim3(TPB), 0, stream>>>(Af, Bf, minbuf);

  // 3) finalize: mean(dist1) + mean(dist2)
  const float scale = 1.0f / (float)TOTAL;
  finalize_kernel<<<dim3(2 * TOTAL / TPB), dim3(TPB), 0, stream>>>(minbuf, out, scale);
}

// Round 12
// 55.753 us; speedup vs baseline: 1.7845x; 1.7845x over previous
//
#include <hip/hip_runtime.h>
#include <math.h>

#define BATCH 4
#define NPTS  8192
#define TOTAL (BATCH * NPTS)            // 32768 points per set
#define TPB   256

#define WPB    4                        // waves per block
#define ROWS_PER_BLOCK (32 * WPB)       // 128 set1 rows per block
#define COLCH  8                        // set2 sweep chunks
#define SWEEP  (NPTS / COLCH)           // 1024 set2 cols per wave sweep
#define NT     (SWEEP / 32)             // 32 B-tiles per sweep

typedef __bf16 bf16v8 __attribute__((ext_vector_type(8)));
typedef float  f32x16 __attribute__((ext_vector_type(16)));

// ws layout:
//   Af: ushort[TOTAL*16] @ 0    (1 MB)  A-form K-vectors of set1 (rows)
//   Bf: ushort[TOTAL*16] @ 1 MB (1 MB)  B-form K-vectors of set2 (cols)
//   minbuf: uint[2*TOTAL] @ 2 MB (256 KB) dist1 then dist2 (ordered-uint)
//   (1-ahead B prefetch over-reads <=1KB past Bf into minbuf -- mapped, harmless)

__device__ __forceinline__ unsigned f2ord(float f) {
  unsigned b = __float_as_uint(f);
  return ((int)b >= 0) ? (b ^ 0x80000000u) : ~b;
}
__device__ __forceinline__ float ord2f(unsigned k) {
  unsigned b = (k & 0x80000000u) ? (k ^ 0x80000000u) : ~k;
  return __uint_as_float(b);
}
__device__ __forceinline__ unsigned short f2bf(float f) {   // RNE
  unsigned u = __float_as_uint(f);
  return (unsigned short)((u + 0x7fffu + ((u >> 16) & 1u)) >> 16);
}
__device__ __forceinline__ float bf2f(unsigned short h) {
  return __uint_as_float(((unsigned)h) << 16);
}

// K-slot pairing (A[k]*B[k]), verified absmax 0 since R4:
//  k0-2: ah*ch   k3-5: al*ch   k6-8: ah*cl   (c = -2b)
//  k9,10: sq_a{h,l} * 1,1      k11,12: 1,1 * sq_b{h,l}     k13-15: 0
// One thread packs A-form of x1[i] AND B-form of x2[i].
__global__ __launch_bounds__(TPB) void pack_kernel(
    const float* __restrict__ x1, const float* __restrict__ x2,
    unsigned short* __restrict__ Af, unsigned short* __restrict__ Bf,
    unsigned* __restrict__ minbuf, float* __restrict__ out) {
  int i = blockIdx.x * TPB + threadIdx.x;   // 0 .. TOTAL-1
  if (i == 0) out[0] = 0.0f;
  minbuf[i] = 0xFFFFFFFFu;
  minbuf[TOTAL + i] = 0xFFFFFFFFu;
  const unsigned short one = 0x3F80;

  // A-form from set1
  {
    float x = x1[3 * i + 0], y = x1[3 * i + 1], z = x1[3 * i + 2];
    float sq = fmaf(x, x, fmaf(y, y, z * z));
    unsigned short sh = f2bf(sq);
    unsigned short sl = f2bf(sq - bf2f(sh));
    unsigned short hx = f2bf(x), hy = f2bf(y), hz = f2bf(z);
    unsigned short lx = f2bf(x - bf2f(hx)), ly = f2bf(y - bf2f(hy)), lz = f2bf(z - bf2f(hz));
    unsigned short v[16] = {hx, hy, hz, lx, ly, lz, hx, hy, hz,
                            sh, sl, one, one, 0, 0, 0};
    uint4* dst = (uint4*)(Af + (size_t)i * 16);
    uint4 w0, w1;
    w0.x = v[0] | ((unsigned)v[1] << 16);  w0.y = v[2] | ((unsigned)v[3] << 16);
    w0.z = v[4] | ((unsigned)v[5] << 16);  w0.w = v[6] | ((unsigned)v[7] << 16);
    w1.x = v[8] | ((unsigned)v[9] << 16);  w1.y = v[10] | ((unsigned)v[11] << 16);
    w1.z = v[12] | ((unsigned)v[13] << 16); w1.w = v[14] | ((unsigned)v[15] << 16);
    dst[0] = w0; dst[1] = w1;
  }
  // B-form from set2
  {
    float x = x2[3 * i + 0], y = x2[3 * i + 1], z = x2[3 * i + 2];
    float sq = fmaf(x, x, fmaf(y, y, z * z));
    unsigned short sh = f2bf(sq);
    unsigned short sl = f2bf(sq - bf2f(sh));
    float cx = -2.0f * x, cy = -2.0f * y, cz = -2.0f * z;
    unsigned short chx = f2bf(cx), chy = f2bf(cy), chz = f2bf(cz);
    unsigned short clx = f2bf(cx - bf2f(chx)), cly = f2bf(cy - bf2f(chy)), clz = f2bf(cz - bf2f(chz));
    unsigned short v[16] = {chx, chy, chz, chx, chy, chz, clx, cly, clz,
                            one, one, sh, sl, 0, 0, 0};
    uint4* dst = (uint4*)(Bf + (size_t)i * 16);
    uint4 w0, w1;
    w0.x = v[0] | ((unsigned)v[1] << 16);  w0.y = v[2] | ((unsigned)v[3] << 16);
    w0.z = v[4] | ((unsigned)v[5] << 16);  w0.w = v[6] | ((unsigned)v[7] << 16);
    w1.x = v[8] | ((unsigned)v[9] << 16);  w1.y = v[10] | ((unsigned)v[11] << 16);
    w1.z = v[12] | ((unsigned)v[13] << 16); w1.w = v[14] | ((unsigned)v[15] << 16);
    dst[0] = w0; dst[1] = w1;
  }
}

// COMBINED single pass, NO inner-loop global traffic:
//  - dist1: elementwise rowacc fmin (AGPR-read legal), butterfly once/sweep.
//  - dist2: per-tile fold -> plain LDS store (each wave writes each of its
//    1024 sweep cols EXACTLY once -> no atomic, no RMW, bank-conflict-free),
//    block-end 4-way fold + one global atomicMin per col (R5-proven pattern).
__global__ __launch_bounds__(TPB, 6) void min_kernel(
    const unsigned short* __restrict__ Af, const unsigned short* __restrict__ Bf,
    unsigned* __restrict__ minbuf) {
  __shared__ float colmin[WPB][SWEEP];   // 16 KB
  const int b   = blockIdx.z;
  const int tid = threadIdx.x;
  const int wave = tid >> 6, lane = tid & 63;
  const int g = lane >> 5, l31 = lane & 31;

  const int rowbase = blockIdx.x * ROWS_PER_BLOCK + wave * 32;  // set1 rows
  const int colbase = blockIdx.y * SWEEP;                        // set2 cols

  // fixed A fragment: this wave's 32 set1 rows
  const bf16v8 af = *((const bf16v8*)Af + (size_t)(b * NPTS + rowbase + l31) * 2 + g);

  f32x16 zc;
#pragma unroll
  for (int q = 0; q < 16; ++q) zc[q] = 0.0f;

  float rowacc[16];
#pragma unroll
  for (int q = 0; q < 16; ++q) rowacc[q] = INFINITY;

  const bf16v8* bp = (const bf16v8*)Bf + (size_t)(b * NPTS + colbase + l31) * 2 + g;

  bf16v8 bcur = bp[0];
  for (int ti = 0; ti < NT; ++ti) {
    bf16v8 bnext = bp[64];                 // 1-ahead prefetch (last iter dead)
    f32x16 acc = __builtin_amdgcn_mfma_f32_32x32x16_bf16(af, bcur, zc, 0, 0, 0);

    // dist1 side: elementwise running min (16 ops, single-AGPR each)
#pragma unroll
    for (int q = 0; q < 16; ++q) rowacc[q] = fminf(rowacc[q], acc[q]);

    // dist2 side: fold 16 rows -> 1, two parallel chains (single-AGPR each)
    float ce = acc[0], co = acc[1];
#pragma unroll
    for (int k = 1; k < 8; ++k) {
      ce = fminf(ce, acc[2 * k]);
      co = fminf(co, acc[2 * k + 1]);
    }
    float m = fminf(ce, co);
    m = fminf(m, __shfl_xor(m, 32));       // merge g-halves (all 32 rows)
    if (g == 0) colmin[wave][ti * 32 + l31] = m;   // plain store, lane==bank

    bcur = bnext;
    bp += 64;
  }

  // dist1 tail: butterfly min across the 32 col-lanes, once per sweep
#pragma unroll
  for (int q = 0; q < 16; ++q) {
    float v = rowacc[q];
    v = fminf(v, __shfl_xor(v, 16));
    v = fminf(v, __shfl_xor(v, 8));
    v = fminf(v, __shfl_xor(v, 4));
    v = fminf(v, __shfl_xor(v, 2));
    v = fminf(v, __shfl_xor(v, 1));
    if (l31 == 0) {
      int row = rowbase + (q & 3) + 8 * (q >> 2) + 4 * g;
      atomicMin(&minbuf[b * NPTS + row], f2ord(v));
    }
  }

  // dist2 flush: fold the 4 waves' values, one global atomic per col
  __syncthreads();
  unsigned* __restrict__ d2 = minbuf + TOTAL + b * NPTS + colbase;
  for (int k = tid; k < SWEEP; k += TPB) {
    float m = fminf(fminf(colmin[0][k], colmin[1][k]),
                    fminf(colmin[2][k], colmin[3][k]));
    atomicMin(&d2[k], f2ord(m));
  }
}

__global__ __launch_bounds__(TPB) void finalize_kernel(
    const unsigned* __restrict__ minbuf, float* __restrict__ out, float scale) {
  int idx = blockIdx.x * TPB + threadIdx.x;   // 0 .. 2*TOTAL-1
  float v = ord2f(minbuf[idx]) * scale;
  for (int off = 32; off > 0; off >>= 1) v += __shfl_down(v, off);
  __shared__ float ls[TPB / 64];
  if ((threadIdx.x & 63) == 0) ls[threadIdx.x >> 6] = v;
  __syncthreads();
  if (threadIdx.x == 0) {
    float t = 0.0f;
#pragma unroll
    for (int w = 0; w < TPB / 64; ++w) t += ls[w];
    atomicAdd(out, t);
  }
}

extern "C" void kernel_launch(void* const* d_in, const int* in_sizes, int n_in,
                              void* d_out, int out_size, void* d_ws, size_t ws_size,
                              hipStream_t stream) {
  const float* xyz1 = (const float*)d_in[0];
  const float* xyz2 = (const float*)d_in[1];
  float* out = (float*)d_out;

  char* ws = (char*)d_ws;
  unsigned short* Af = (unsigned short*)(ws);
  unsigned short* Bf = (unsigned short*)(ws + (size_t)TOTAL * 32);
  unsigned*   minbuf = (unsigned*)(ws + (size_t)2 * TOTAL * 32);

  // 1) pack set1 A-form + set2 B-form + init minbuf + zero out
  pack_kernel<<<dim3(TOTAL / TPB), dim3(TPB), 0, stream>>>(
      xyz1, xyz2, Af, Bf, minbuf, out);

  // 2) ONE combined pass over the pair space: 64 x 8 x 4 = 2048 blocks
  dim3 mgrid(NPTS / ROWS_PER_BLOCK, COLCH, BATCH);
  min_kernel<<<mgrid, dim3(TPB), 0, stream>>>(Af, Bf, minbuf);

  // 3) finalize: mean(dist1) + mean(dist2)
  const float scale = 1.0f / (float)TOTAL;
  finalize_kernel<<<dim3(2 * TOTAL / TPB), dim3(TPB), 0, stream>>>(minbuf, out, scale);
}

// Round 13
// 40.857 us; speedup vs baseline: 2.4351x; 1.3646x over previous
//
#include <hip/hip_runtime.h>
#include <math.h>

#define BATCH 4
#define NPTS  8192
#define TOTAL (BATCH * NPTS)            // 32768 points per set
#define TPB   256

#define WPB    4                        // waves per block
#define ROWS_PER_BLOCK (32 * WPB)       // 128 set1 rows per block
#define COLCH  8                        // set2 sweep chunks
#define SWEEP  (NPTS / COLCH)           // 1024 set2 cols per wave sweep
#define NT     (SWEEP / 32)             // 32 B-tiles per sweep (even)

typedef __bf16 bf16v8 __attribute__((ext_vector_type(8)));
typedef float  f32x16 __attribute__((ext_vector_type(16)));

// ws layout:
//   Af: ushort[TOTAL*16] @ 0    (1 MB)  A-form K-vectors of set1 (rows)
//   Bf: ushort[TOTAL*16] @ 1 MB (1 MB)  B-form K-vectors of set2 (cols)
//   minbuf: uint[2*TOTAL] @ 2 MB (256 KB) dist1 then dist2 (ordered-uint)
//   (2-ahead B prefetch over-reads <=2KB past Bf into minbuf -- mapped, harmless)

__device__ __forceinline__ unsigned f2ord(float f) {
  unsigned b = __float_as_uint(f);
  return ((int)b >= 0) ? (b ^ 0x80000000u) : ~b;
}
__device__ __forceinline__ float ord2f(unsigned k) {
  unsigned b = (k & 0x80000000u) ? (k ^ 0x80000000u) : ~k;
  return __uint_as_float(b);
}
__device__ __forceinline__ unsigned short f2bf(float f) {   // RNE
  unsigned u = __float_as_uint(f);
  return (unsigned short)((u + 0x7fffu + ((u >> 16) & 1u)) >> 16);
}
__device__ __forceinline__ float bf2f(unsigned short h) {
  return __uint_as_float(((unsigned)h) << 16);
}
__device__ __forceinline__ float mf3(float a, float b, float c) {
  return fminf(fminf(a, b), c);   // ISel fuses to v_min3_f32
}

// K-slot pairing (A[k]*B[k]), verified absmax 0 since R4:
//  k0-2: ah*ch   k3-5: al*ch   k6-8: ah*cl   (c = -2b)
//  k9,10: sq_a{h,l} * 1,1      k11,12: 1,1 * sq_b{h,l}     k13-15: 0
__global__ __launch_bounds__(TPB) void pack_kernel(
    const float* __restrict__ x1, const float* __restrict__ x2,
    unsigned short* __restrict__ Af, unsigned short* __restrict__ Bf,
    unsigned* __restrict__ minbuf, float* __restrict__ out) {
  int i = blockIdx.x * TPB + threadIdx.x;   // 0 .. TOTAL-1
  if (i == 0) out[0] = 0.0f;
  minbuf[i] = 0xFFFFFFFFu;
  minbuf[TOTAL + i] = 0xFFFFFFFFu;
  const unsigned short one = 0x3F80;

  // A-form from set1
  {
    float x = x1[3 * i + 0], y = x1[3 * i + 1], z = x1[3 * i + 2];
    float sq = fmaf(x, x, fmaf(y, y, z * z));
    unsigned short sh = f2bf(sq);
    unsigned short sl = f2bf(sq - bf2f(sh));
    unsigned short hx = f2bf(x), hy = f2bf(y), hz = f2bf(z);
    unsigned short lx = f2bf(x - bf2f(hx)), ly = f2bf(y - bf2f(hy)), lz = f2bf(z - bf2f(hz));
    unsigned short v[16] = {hx, hy, hz, lx, ly, lz, hx, hy, hz,
                            sh, sl, one, one, 0, 0, 0};
    uint4* dst = (uint4*)(Af + (size_t)i * 16);
    uint4 w0, w1;
    w0.x = v[0] | ((unsigned)v[1] << 16);  w0.y = v[2] | ((unsigned)v[3] << 16);
    w0.z = v[4] | ((unsigned)v[5] << 16);  w0.w = v[6] | ((unsigned)v[7] << 16);
    w1.x = v[8] | ((unsigned)v[9] << 16);  w1.y = v[10] | ((unsigned)v[11] << 16);
    w1.z = v[12] | ((unsigned)v[13] << 16); w1.w = v[14] | ((unsigned)v[15] << 16);
    dst[0] = w0; dst[1] = w1;
  }
  // B-form from set2
  {
    float x = x2[3 * i + 0], y = x2[3 * i + 1], z = x2[3 * i + 2];
    float sq = fmaf(x, x, fmaf(y, y, z * z));
    unsigned short sh = f2bf(sq);
    unsigned short sl = f2bf(sq - bf2f(sh));
    float cx = -2.0f * x, cy = -2.0f * y, cz = -2.0f * z;
    unsigned short chx = f2bf(cx), chy = f2bf(cy), chz = f2bf(cz);
    unsigned short clx = f2bf(cx - bf2f(chx)), cly = f2bf(cy - bf2f(chy)), clz = f2bf(cz - bf2f(chz));
    unsigned short v[16] = {chx, chy, chz, chx, chy, chz, clx, cly, clz,
                            one, one, sh, sl, 0, 0, 0};
    uint4* dst = (uint4*)(Bf + (size_t)i * 16);
    uint4 w0, w1;
    w0.x = v[0] | ((unsigned)v[1] << 16);  w0.y = v[2] | ((unsigned)v[3] << 16);
    w0.z = v[4] | ((unsigned)v[5] << 16);  w0.w = v[6] | ((unsigned)v[7] << 16);
    w1.x = v[8] | ((unsigned)v[9] << 16);  w1.y = v[10] | ((unsigned)v[11] << 16);
    w1.z = v[12] | ((unsigned)v[13] << 16); w1.w = v[14] | ((unsigned)v[15] << 16);
    dst[0] = w0; dst[1] = w1;
  }
}

// Per-tile consume: 16 elementwise fmin (dist1) + balanced 16->1 min3 fold
// (dist2) + one plain LDS store. No shfl, no branch, no atomics in loop.
#define CONSUME(ACC, TI)                                                   \
  do {                                                                     \
    _Pragma("unroll")                                                      \
    for (int q = 0; q < 16; ++q) rowacc[q] = fminf(rowacc[q], (ACC)[q]);   \
    float t0 = mf3((ACC)[0],  (ACC)[1],  (ACC)[2]);                        \
    float t1 = mf3((ACC)[3],  (ACC)[4],  (ACC)[5]);                        \
    float t2 = mf3((ACC)[6],  (ACC)[7],  (ACC)[8]);                        \
    float t3 = mf3((ACC)[9],  (ACC)[10], (ACC)[11]);                       \
    float t4 = mf3((ACC)[12], (ACC)[13], (ACC)[14]);                       \
    myrow[(TI) * 32 + l31] = fminf(mf3(t0, t1, (ACC)[15]), mf3(t2, t3, t4)); \
  } while (0)

// COMBINED single pass. __launch_bounds__(256,4): 128-reg budget so the
// AV-class MFMA accumulators land in VGPRs (VGPR-form) -- no accvgpr traffic.
// Two-stage named pipeline: mfma(tile k+1) issues before consume(tile k).
__global__ __launch_bounds__(TPB, 4) void min_kernel(
    const unsigned short* __restrict__ Af, const unsigned short* __restrict__ Bf,
    unsigned* __restrict__ minbuf) {
  __shared__ float colmin[2 * WPB][SWEEP];   // 32 KB
  const int b   = blockIdx.z;
  const int tid = threadIdx.x;
  const int wave = tid >> 6, lane = tid & 63;
  const int g = lane >> 5, l31 = lane & 31;

  const int rowbase = blockIdx.x * ROWS_PER_BLOCK + wave * 32;  // set1 rows
  const int colbase = blockIdx.y * SWEEP;                        // set2 cols

  const bf16v8 af = *((const bf16v8*)Af + (size_t)(b * NPTS + rowbase + l31) * 2 + g);

  f32x16 zc;
#pragma unroll
  for (int q = 0; q < 16; ++q) zc[q] = 0.0f;

  const bf16v8* bp = (const bf16v8*)Bf + (size_t)(b * NPTS + colbase + l31) * 2 + g;
  float* myrow = &colmin[2 * wave + g][0];

  // prologue: tiles 0..2 staged, tile 0 issued
  bf16v8 b0 = bp[0];
  bf16v8 bA = bp[64];     // tile 1
  bf16v8 bB = bp[128];    // tile 2
  f32x16 acc0 = __builtin_amdgcn_mfma_f32_32x32x16_bf16(b0 /*dummy order*/, b0, zc, 0, 0, 0);
  // (real issue below -- keep rowacc init between mfma and first consume)
  acc0 = __builtin_amdgcn_mfma_f32_32x32x16_bf16(af, b0, zc, 0, 0, 0);

  float rowacc[16];
#pragma unroll
  for (int q = 0; q < 16; ++q) rowacc[q] = INFINITY;

  f32x16 acc1;
  for (int ti = 0; ti < NT - 2; ti += 2) {
    acc1 = __builtin_amdgcn_mfma_f32_32x32x16_bf16(af, bA, zc, 0, 0, 0);  // ti+1
    bA = bp[192];                                  // prefetch tile ti+3
    CONSUME(acc0, ti);
    acc0 = __builtin_amdgcn_mfma_f32_32x32x16_bf16(af, bB, zc, 0, 0, 0);  // ti+2
    bB = bp[256];                                  // prefetch tile ti+4
    CONSUME(acc1, ti + 1);
    bp += 128;
  }
  acc1 = __builtin_amdgcn_mfma_f32_32x32x16_bf16(af, bA, zc, 0, 0, 0);    // tile 31
  CONSUME(acc0, NT - 2);
  CONSUME(acc1, NT - 1);

  // dist1 tail: butterfly min across the 32 col-lanes, once per sweep
#pragma unroll
  for (int q = 0; q < 16; ++q) {
    float v = rowacc[q];
    v = fminf(v, __shfl_xor(v, 16));
    v = fminf(v, __shfl_xor(v, 8));
    v = fminf(v, __shfl_xor(v, 4));
    v = fminf(v, __shfl_xor(v, 2));
    v = fminf(v, __shfl_xor(v, 1));
    if (l31 == 0) {
      int row = rowbase + (q & 3) + 8 * (q >> 2) + 4 * g;
      atomicMin(&minbuf[b * NPTS + row], f2ord(v));
    }
  }

  // dist2 flush: fold the 8 half-wave rows, one global atomic per col
  __syncthreads();
  unsigned* __restrict__ d2 = minbuf + TOTAL + b * NPTS + colbase;
  for (int k = tid; k < SWEEP; k += TPB) {
    float m0 = mf3(colmin[0][k], colmin[1][k], colmin[2][k]);
    float m1 = mf3(colmin[3][k], colmin[4][k], colmin[5][k]);
    float m  = fminf(mf3(m0, m1, colmin[6][k]), colmin[7][k]);
    atomicMin(&d2[k], f2ord(m));
  }
}

__global__ __launch_bounds__(TPB) void finalize_kernel(
    const unsigned* __restrict__ minbuf, float* __restrict__ out, float scale) {
  int idx = blockIdx.x * TPB + threadIdx.x;   // 0 .. 2*TOTAL-1
  float v = ord2f(minbuf[idx]) * scale;
  for (int off = 32; off > 0; off >>= 1) v += __shfl_down(v, off);
  __shared__ float ls[TPB / 64];
  if ((threadIdx.x & 63) == 0) ls[threadIdx.x >> 6] = v;
  __syncthreads();
  if (threadIdx.x == 0) {
    float t = 0.0f;
#pragma unroll
    for (int w = 0; w < TPB / 64; ++w) t += ls[w];
    atomicAdd(out, t);
  }
}

extern "C" void kernel_launch(void* const* d_in, const int* in_sizes, int n_in,
                              void* d_out, int out_size, void* d_ws, size_t ws_size,
                              hipStream_t stream) {
  const float* xyz1 = (const float*)d_in[0];
  const float* xyz2 = (const float*)d_in[1];
  float* out = (float*)d_out;

  char* ws = (char*)d_ws;
  unsigned short* Af = (unsigned short*)(ws);
  unsigned short* Bf = (unsigned short*)(ws + (size_t)TOTAL * 32);
  unsigned*   minbuf = (unsigned*)(ws + (size_t)2 * TOTAL * 32);

  // 1) pack set1 A-form + set2 B-form + init minbuf + zero out
  pack_kernel<<<dim3(TOTAL / TPB), dim3(TPB), 0, stream>>>(
      xyz1, xyz2, Af, Bf, minbuf, out);

  // 2) ONE combined pass over the pair space: 64 x 8 x 4 = 2048 blocks
  dim3 mgrid(NPTS / ROWS_PER_BLOCK, COLCH, BATCH);
  min_kernel<<<mgrid, dim3(TPB), 0, stream>>>(Af, Bf, minbuf);

  // 3) finalize: mean(dist1) + mean(dist2)
  const float scale = 1.0f / (float)TOTAL;
  finalize_kernel<<<dim3(2 * TOTAL / TPB), dim3(TPB), 0, stream>>>(minbuf, out, scale);
}